// Round 13
// baseline (93.703 us; speedup 1.0000x reference)
//
#include <hip/hip_runtime.h>
#include <math.h>

#define NATOMS    128
#define NSEG      7875     // segments: i in [0,124], j in [i+2,126]
#define NSEG_PAD  8192
#define NPAIRSEG  3969     // j-adjacent segment pairs: sum_i ceil((125-i)/2)
#define NPAIR_PAD 4096
#define NPAIR     8128     // atom pairs (a,b), 0 <= a < b <= 127
#define OUT_PER_B 16256    // 128*127 (row-major, diagonal skipped)
#define BLOCK     1024

typedef float v2f __attribute__((ext_vector_type(2)));
__device__ __forceinline__ v2f mk2(float a, float b) { v2f r; r.x = a; r.y = b; return r; }

struct P3 { v2f x, y, z; };
__device__ __forceinline__ P3 pcross(P3 a, P3 b) {
    return {a.y * b.z - a.z * b.y, a.z * b.x - a.x * b.z, a.x * b.y - a.y * b.x};
}
__device__ __forceinline__ v2f pdot(P3 a, P3 b) { return a.x * b.x + a.y * b.y + a.z * b.z; }
__device__ __forceinline__ v2f prsq(v2f q) {
    v2f r; r.x = __builtin_amdgcn_rsqf(q.x); r.y = __builtin_amdgcn_rsqf(q.y); return r;
}
__device__ __forceinline__ v2f pclip1(v2f x) {
    return __builtin_elementwise_min(__builtin_elementwise_max(x, mk2(-1.f, -1.f)),
                                     mk2(1.f, 1.f));
}

// Packed 4-term branchless asin, A&S 4.4.45 (|err| <= 6.8e-5; threshold 5.9e-2).
__device__ __forceinline__ v2f fast_asin2(v2f x) {
    v2f a = __builtin_elementwise_abs(x);
    v2f p = mk2(-0.0187293f, -0.0187293f);
    p = p * a + mk2( 0.0742610f,  0.0742610f);
    p = p * a + mk2(-0.2121144f, -0.2121144f);
    p = p * a + mk2( 1.5707288f,  1.5707288f);
    v2f om = mk2(1.0f, 1.0f) - a;
    v2f sq; sq.x = __builtin_amdgcn_sqrtf(om.x); sq.y = __builtin_amdgcn_sqrtf(om.y);
    v2f r = mk2(1.57079632679f, 1.57079632679f) - sq * p;
    return __builtin_elementwise_copysign(r, x);
}

__device__ __forceinline__ int seg_row_base(int i) { return 125 * i - (__umul24(i, i - 1) >> 1); }
__device__ __forceinline__ int pair_row_base(int a) { return (__umul24(a, 255 - a) >> 1); }

// Writhe for the j-adjacent pair (i,j) [x-lane] and (i,j+1) [y-lane].
// 5 points / 15 LDS reads feed both lanes; displacement bundles
//   a_k = p[j+k]-p[i], b_k = p[j+k]-p[i+1]  (k=0..2, 18 scalar subs)
// give u0={a0,a1}, u1={a1,a2}, u2={b0,b1}, u3={b1,b2} as free pairings.
// Sign via the exact identity cross(p3-p2, p1-p0).u0 = -(u3 x u2).u0 = -n2.u0.
// Per-lane arithmetic is bit-identical to the unpaired version.
__device__ __forceinline__ v2f writhe_pair_j(int i, int j, const float* sx,
                                             const float* sy, const float* sz) {
    int jc2 = min(j + 2, 127);          // clamp; y-lane is masked when j==126
    float pix = sx[i],     piy = sy[i],     piz = sz[i];
    float qix = sx[i + 1], qiy = sy[i + 1], qiz = sz[i + 1];
    float P0x = sx[j],     P0y = sy[j],     P0z = sz[j];
    float P1x = sx[j + 1], P1y = sy[j + 1], P1z = sz[j + 1];
    float P2x = sx[jc2],   P2y = sy[jc2],   P2z = sz[jc2];

    float a0x = P0x - pix, a0y = P0y - piy, a0z = P0z - piz;
    float a1x = P1x - pix, a1y = P1y - piy, a1z = P1z - piz;
    float a2x = P2x - pix, a2y = P2y - piy, a2z = P2z - piz;
    float b0x = P0x - qix, b0y = P0y - qiy, b0z = P0z - qiz;
    float b1x = P1x - qix, b1y = P1y - qiy, b1z = P1z - qiz;
    float b2x = P2x - qix, b2y = P2y - qiy, b2z = P2z - qiz;

    P3 u0 = {mk2(a0x, a1x), mk2(a0y, a1y), mk2(a0z, a1z)};
    P3 u1 = {mk2(a1x, a2x), mk2(a1y, a2y), mk2(a1z, a2z)};
    P3 u2 = {mk2(b0x, b1x), mk2(b0y, b1y), mk2(b0z, b1z)};
    P3 u3 = {mk2(b1x, b2x), mk2(b1y, b2y), mk2(b1z, b2z)};

    P3 n0 = pcross(u0, u1);
    P3 n1 = pcross(u1, u3);
    P3 n2 = pcross(u3, u2);
    P3 n3 = pcross(u2, u0);

    v2f q0 = pdot(n0, n0);
    v2f q1 = pdot(n1, n1);
    v2f q2 = pdot(n2, n2);
    v2f q3 = pdot(n3, n3);

    v2f c0 = pclip1(pdot(n0, n1) * prsq(q0 * q1));
    v2f c1 = pclip1(pdot(n1, n2) * prsq(q1 * q2));
    v2f c2 = pclip1(pdot(n2, n3) * prsq(q2 * q3));
    v2f c3 = pclip1(pdot(n3, n0) * prsq(q3 * q0));

    v2f sd = pdot(n2, u0);     // = -(reference sd); sign folded below
    v2f omega = fast_asin2(c0) + fast_asin2(c1) + fast_asin2(c2) + fast_asin2(c3);

    v2f sgn;
    sgn.x = (sd.x > 0.f) ? -1.f : ((sd.x < 0.f) ? 1.f : 0.f);
    sgn.y = (sd.y > 0.f) ? -1.f : ((sd.y < 0.f) ? 1.f : 0.f);

    return omega * sgn * mk2(0.15915494309189535f, 0.15915494309189535f);
}

// One block per batch.
// Phase 0: walk all segments once; emit tpair entries (pair-start segments,
//          (j-i) even) at closed-form slot R(i)+((j-i-2)>>1), R(i)=63i-i*i/4;
//          also build spair (atom-pair -> (a,b)).
// Phase A: j-adjacent packed writhe -> swr; 2 independent packed calls per
//          iteration x 2 iterations = 4 entries = 8 segments/thread.
// Phase D: per atom-pair gather from swr + dual store (verified round 11).
// LDS: coords 1.5K + swr 32K + tpair 8K + spair 16.25K ~= 57.8 KB; 2 blocks/CU.
__global__ __launch_bounds__(BLOCK, 8) void writhe_fused(
    const float* __restrict__ xyz,       // (B, 128, 3)
    float*       __restrict__ out)       // (B, 16256)
{
    __shared__ float sx[NATOMS], sy[NATOMS], sz[NATOMS];
    __shared__ float swr[NSEG_PAD];
    __shared__ unsigned short tpair[NPAIR_PAD];
    __shared__ unsigned short spair[NPAIR];

    const int b = blockIdx.x;
    const int t = threadIdx.x;

    if (t < 3 * NATOMS) {
        float v = xyz[(size_t)b * (3 * NATOMS) + t];
        int a = t / 3, c = t - 3 * a;
        if (c == 0) sx[a] = v; else if (c == 1) sy[a] = v; else sz[a] = v;
    }

    // ---------- Phase 0a: segment walk -> tpair ----------
    {
        int s = t * 8;
        if (s < NSEG) {
            int i = (int)((251.0f - __builtin_amdgcn_sqrtf(63001.0f - 8.0f * (float)s)) * 0.5f);
            i = max(i, 0);
            i += (seg_row_base(i + 1) <= s);
            i += (seg_row_base(i + 1) <= s);
            i -= (seg_row_base(i) > s);
            i -= (seg_row_base(i) > s);
            int j = s - seg_row_base(i) + i + 2;
            #pragma unroll
            for (int k = 0; k < 8; ++k) {
                if (s < NSEG && (((j - i) & 1) == 0)) {
                    int q = 63 * i - (__umul24(i, i) >> 2) + ((j - i - 2) >> 1);
                    tpair[q] = (unsigned short)((i << 7) | j);
                }
                ++s; ++j;
                if (j > 126) { ++i; j = i + 2; }
            }
        }
        // pad: recomputes segment 7874 (same value, benign), y-lane masked
        if (t < NPAIR_PAD - NPAIRSEG) tpair[NPAIRSEG + t] = (unsigned short)((124 << 7) | 126);
    }
    // ---------- Phase 0b: build spair ----------
    {
        int p = t * 8;
        if (p < NPAIR) {
            int a = (int)((255.0f - __builtin_amdgcn_sqrtf(65025.0f - 8.0f * (float)p)) * 0.5f);
            a = max(a, 0);
            a += (pair_row_base(a + 1) <= p);
            a += (pair_row_base(a + 1) <= p);
            a -= (pair_row_base(a) > p);
            a -= (pair_row_base(a) > p);
            int bb = a + 1 + (p - pair_row_base(a));
            #pragma unroll
            for (int k = 0; k < 8; ++k) {
                if (p < NPAIR) spair[p] = (unsigned short)((a << 7) | bb);
                ++p; ++bb;
                if (bb > 127) { ++a; bb = a + 1; }
            }
        }
    }
    __syncthreads();

    // ---------- Phase A: j-adjacent packed writhe, 2 chains x 2 iterations ----------
    #pragma unroll
    for (int g = 0; g < 2; ++g) {
        int e1 = g * 2048 + t;           // < 4096: unconditional
        int e2 = e1 + 1024;
        unsigned k1 = tpair[e1], k2 = tpair[e2];
        int j1 = (int)(k1 & 127u), i1 = (int)(k1 >> 7);
        int j2 = (int)(k2 & 127u), i2 = (int)(k2 >> 7);

        v2f w1 = writhe_pair_j(i1, j1, sx, sy, sz);
        v2f w2 = writhe_pair_j(i2, j2, sx, sy, sz);

        int s1 = seg_row_base(i1) + j1 - i1 - 2;
        int s2 = seg_row_base(i2) + j2 - i2 - 2;
        swr[s1] = w1.x;
        if (j1 < 126) swr[s1 + 1] = w1.y;
        swr[s2] = w2.x;
        if (j2 < 126) swr[s2 + 1] = w2.y;
    }
    __syncthreads();

    // ---------- Phase D: per atom-pair gather + dual store ----------
    float* ob = out + (size_t)b * OUT_PER_B;
    for (int p = t; p < NPAIR; p += BLOCK) {
        unsigned pk = spair[p];
        int bb = (int)(pk & 127u);
        int a  = (int)(pk >> 7);

        // segment ids for (i,j) in {a-1,a} x {b-1,b}; s(i,j)=base(i)+j-i-2
        int am1 = a - 1;
        int s00 = 125 * am1 - ((am1 * (am1 - 1)) >> 1) + bb - a - 2;  // (a-1, b-1)
        int s10 = s00 + 125 - a;                                      // (a,   b-1)

        bool v00 = (a >= 1) && (a <= 125) && (bb >= a + 2);
        bool v01 = (a >= 1) && (a <= 125) && (bb <= 126);
        bool v10 = (a <= 124) && (bb >= a + 3);
        bool v11 = (a <= 124) && (bb <= 126) && (bb >= a + 2);

        int c00 = min(max(s00,     0), NSEG - 1);
        int c01 = min(max(s00 + 1, 0), NSEG - 1);
        int c10 = min(max(s10,     0), NSEG - 1);
        int c11 = min(max(s10 + 1, 0), NSEG - 1);

        float sum = (v00 ? swr[c00] : 0.0f) + (v01 ? swr[c01] : 0.0f)
                  + (v10 ? swr[c10] : 0.0f) + (v11 ? swr[c11] : 0.0f);

        int k1 = 127 * a + bb - 1;   // (r,c) = (a,b), r < c
        int k2 = 127 * bb + a;       // (r,c) = (b,a), r > c
        ob[k1] = sum;
        ob[k2] = sum;
    }
}

extern "C" void kernel_launch(void* const* d_in, const int* in_sizes, int n_in,
                              void* d_out, int out_size, void* d_ws, size_t ws_size,
                              hipStream_t stream) {
    const float* xyz = (const float*)d_in[0];
    float*       out = (float*)d_out;

    int B = in_sizes[0] / (NATOMS * 3);   // 512 for the reference shapes
    writhe_fused<<<B, BLOCK, 0, stream>>>(xyz, out);
}